// Round 5
// baseline (10191.975 us; speedup 1.0000x reference)
//
#include <hip/hip_runtime.h>
#include <math.h>

// ---------------------------------------------------------------------------
// RNNv2 round 12: flag-based signal/data separation (round-9/10 design),
// retried with a fail-soft stall cap. Rationale:
//   - r11 proved poll-traffic congestion is real: escalating sleep backoff
//     alone bought -22% (6796 -> 5272us). The flag design cuts poll demand
//     ~1000x further (256B coalesced flag read per WG-iter vs 8KB data
//     sweeps) AND removes sleep quantization (tight spin is affordable when
//     traffic is tiny) -> attacks both confirmed costs.
//   - stall cap (1<<22 poll iters) turns any protocol stall into a wrong-
//     answer completion (passed:false + counters) instead of a dead
//     container: r9/r10's failure mode becomes diagnosable.
// Protocol:
//   ready[l*64+w] = t  <=>  "h_l(t-1) rows of WG w visible at L3".
//   Producer: data ST (sc1) -> s_waitcnt vmcnt(0) -> barrier -> tid0 flag ST.
//   Consumer: wave 0 spins on 64 flags (one per producer WG, lane k -> WG k);
//   after confirm, all waves load data once (agent loads) -> LDS -> compute.
// Flags live in d_out[0..255] (ys region, overwritten by gemm_out later in
// stream order). ws layout unchanged (48MB: xin 16MB + hist 32MB).
// d_out = [ys (S*IN) | h_final (L*H)]
// ---------------------------------------------------------------------------

typedef unsigned int uint32;
typedef unsigned long long uint64;
typedef _Float16 half2_t __attribute__((ext_vector_type(2)));

#define S_LEN 2048
#define IN_SZ 1024
#define HID   2048
#define NLAY  4
#define NWG   256
#define BLK   512
#define H2    1024   // uints per packed h vector (HID/2)

#define LD_AGENT(p)   __hip_atomic_load((p), __ATOMIC_RELAXED, __HIP_MEMORY_SCOPE_AGENT)
#define ST_AGENT(p,v) __hip_atomic_store((p), (v), __ATOMIC_RELAXED, __HIP_MEMORY_SCOPE_AGENT)

__device__ __forceinline__ float dot2(uint32 a, uint32 b, float c) {
    return __builtin_amdgcn_fdot2(__builtin_bit_cast(half2_t, a),
                                  __builtin_bit_cast(half2_t, b), c, false);
}
__device__ __forceinline__ uint32 packh2(float x, float y) {
    half2_t h; h.x = (_Float16)x; h.y = (_Float16)y;   // RNE converts
    return __builtin_bit_cast(uint32, h);
}
__device__ __forceinline__ float fast_tanh(float x) {
#if __has_builtin(__builtin_amdgcn_exp2f) && __has_builtin(__builtin_amdgcn_rcpf)
    // tanh(x) = sign(x) * (1 - 2/(exp2(2*log2e*|x|) + 1)); abs err ~1e-6
    float a = fabsf(x);
    float e = __builtin_amdgcn_exp2f(a * 2.885390081777927f);
    float r = 1.f - 2.f * __builtin_amdgcn_rcpf(e + 1.f);
    return copysignf(r, x);
#else
    return tanhf(x);
#endif
}

__global__ __launch_bounds__(BLK, 2) void rnn_scan(
    const float* __restrict__ Wh,   // [4][H][H]
    const float* __restrict__ Whh,  // [3][H][H]
    const float* __restrict__ xin,  // [S][H]  (x @ Wx^T, fp32)
    const float* __restrict__ Bh,   // [4][H]
    float* __restrict__ hfin,       // [4][H] (tail of d_out)
    uint32* hist,                   // [4][S][H2] packed half2
    uint32* ready)                  // [4][64] per-WG epoch flags, zeroed
{
    __shared__ __align__(16) uint32 sh_own[H2];
    __shared__ __align__(16) uint32 sh_prev[H2];

    const int g   = blockIdx.x;
    const int l   = g >> 6;          // layer 0..3 (wave-uniform)
    const int w   = g & 63;          // wg within layer
    const int tid = threadIdx.x;
    const int v   = tid >> 6;        // wave 0..7
    const int k   = tid & 63;        // lane
    const int r0  = w * 32 + v * 4;  // first of this wave's 4 rows

    // ---- one-time: load + pack weights into registers --------------------
    // Chunk c (0..3): lane k covers cols 8k+512c..+7 = uint4 index k+64c of
    // the packed h row. wA[16*rr + 4c + q] = Wh row rr; wB likewise for Whh.
    uint32 wA[64], wB[64];
    const float4 bh4 = *(const float4*)(Bh + l * HID + r0);

    #pragma unroll
    for (int rr = 0; rr < 4; ++rr) {
        const float* wr = Wh + ((size_t)l * HID + r0 + rr) * HID;
        #pragma unroll
        for (int j = 0; j < 4; ++j) {
            const float* p = wr + 8 * k + 512 * j;
            float4 f0 = *(const float4*)p;
            float4 f1 = *(const float4*)(p + 4);
            wA[16 * rr + 4 * j + 0] = packh2(f0.x, f0.y);
            wA[16 * rr + 4 * j + 1] = packh2(f0.z, f0.w);
            wA[16 * rr + 4 * j + 2] = packh2(f1.x, f1.y);
            wA[16 * rr + 4 * j + 3] = packh2(f1.z, f1.w);
        }
    }
    if (l > 0) {
        #pragma unroll
        for (int rr = 0; rr < 4; ++rr) {
            const float* wr2 = Whh + ((size_t)(l - 1) * HID + r0 + rr) * HID;
            #pragma unroll
            for (int j = 0; j < 4; ++j) {
                const float* p = wr2 + 8 * k + 512 * j;
                float4 f0 = *(const float4*)p;
                float4 f1 = *(const float4*)(p + 4);
                wB[16 * rr + 4 * j + 0] = packh2(f0.x, f0.y);
                wB[16 * rr + 4 * j + 1] = packh2(f0.z, f0.w);
                wB[16 * rr + 4 * j + 2] = packh2(f1.x, f1.y);
                wB[16 * rr + 4 * j + 3] = packh2(f1.z, f1.w);
            }
        }
    }

    uint32* histL = hist + (size_t)l * S_LEN * H2;
    uint32* histP = hist + (size_t)(l - 1) * S_LEN * H2;  // only if l>0
    const bool needPrev = (l > 0);
    // poll targets (wave 0, lane k checks producer-WG k)
    const uint32* rdO = ready + l * 64 + k;
    const uint32* rdP = (l > 0) ? (ready + (l - 1) * 64 + k) : (ready + k);

    // ---- timestep loop ----------------------------------------------------
    for (int t = 0; t < S_LEN; ++t) {
        const bool needOwn = (t > 0);

        // layer 0: prefetch xin quad early (static data)
        float4 xv = make_float4(0.f, 0.f, 0.f, 0.f);
        if (l == 0 && k == 0) xv = *(const float4*)(xin + (size_t)t * HID + r0);

        // signal: this WG's h(t-1) rows are visible (stores drained before
        // the barrier that ended step t-1).
        if (tid == 0 && t > 0) ST_AGENT(&ready[g], (uint32)t);

        // ---- poll (wave 0 only): own layer @ t, prev layer @ t+1 ---------
        if (v == 0 && (needOwn | needPrev)) {
            __builtin_amdgcn_s_setprio(0);
            bool okO = !needOwn, okP = !needPrev;
            const uint32 tO = (uint32)t, tP = (uint32)(t + 1);
            uint32 guard = 0;
            for (;;) {
                if (!okO) okO = (bool)__all(LD_AGENT(rdO) >= tO);
                if (!okP) okP = (bool)__all(LD_AGENT(rdP) >= tP);
                if (okO & okP) break;
                // fail-soft stall cap: never triggers in a healthy run
                // (normal detect < 1e3 iters); turns a protocol stall into
                // a wrong-answer completion instead of a hung container.
                if (++guard > (1u << 22)) break;
            }
            __builtin_amdgcn_s_setprio(1);
        }
        __syncthreads();                 // A: flags confirmed WG-wide

        // ---- stage: one-shot agent loads -> LDS --------------------------
        {
            uint32 a0 = 0, a1 = 0, b0 = 0, b1 = 0;
            if (needOwn) {
                const uint32* pO = histL + (size_t)(t - 1) * H2 + tid;
                a0 = LD_AGENT(pO);
                a1 = LD_AGENT(pO + 512);
            }
            if (needPrev) {
                const uint32* pP = histP + (size_t)t * H2 + tid;
                b0 = LD_AGENT(pP);
                b1 = LD_AGENT(pP + 512);
            }
            if (needOwn)  { sh_own[tid]  = a0; sh_own[tid + 512]  = a1; }
            if (needPrev) { sh_prev[tid] = b0; sh_prev[tid + 512] = b1; }
        }
        __syncthreads();                 // B: LDS staged

        // ---- compute ------------------------------------------------------
        float acc0 = 0.f, acc1 = 0.f, acc2 = 0.f, acc3 = 0.f;

        if (needPrev) {
            #pragma unroll
            for (int c = 0; c < 4; ++c) {
                const uint4 gv = ((const uint4*)sh_prev)[k + 64 * c];
                acc0 = dot2(wB[4 * c + 0], gv.x, acc0);
                acc0 = dot2(wB[4 * c + 1], gv.y, acc0);
                acc0 = dot2(wB[4 * c + 2], gv.z, acc0);
                acc0 = dot2(wB[4 * c + 3], gv.w, acc0);
                acc1 = dot2(wB[16 + 4 * c + 0], gv.x, acc1);
                acc1 = dot2(wB[16 + 4 * c + 1], gv.y, acc1);
                acc1 = dot2(wB[16 + 4 * c + 2], gv.z, acc1);
                acc1 = dot2(wB[16 + 4 * c + 3], gv.w, acc1);
                acc2 = dot2(wB[32 + 4 * c + 0], gv.x, acc2);
                acc2 = dot2(wB[32 + 4 * c + 1], gv.y, acc2);
                acc2 = dot2(wB[32 + 4 * c + 2], gv.z, acc2);
                acc2 = dot2(wB[32 + 4 * c + 3], gv.w, acc2);
                acc3 = dot2(wB[48 + 4 * c + 0], gv.x, acc3);
                acc3 = dot2(wB[48 + 4 * c + 1], gv.y, acc3);
                acc3 = dot2(wB[48 + 4 * c + 2], gv.z, acc3);
                acc3 = dot2(wB[48 + 4 * c + 3], gv.w, acc3);
            }
        }

        if (needOwn) {
            #pragma unroll
            for (int c = 0; c < 4; ++c) {
                const uint4 hv = ((const uint4*)sh_own)[k + 64 * c];
                acc0 = dot2(wA[4 * c + 0], hv.x, acc0);
                acc0 = dot2(wA[4 * c + 1], hv.y, acc0);
                acc0 = dot2(wA[4 * c + 2], hv.z, acc0);
                acc0 = dot2(wA[4 * c + 3], hv.w, acc0);
                acc1 = dot2(wA[16 + 4 * c + 0], hv.x, acc1);
                acc1 = dot2(wA[16 + 4 * c + 1], hv.y, acc1);
                acc1 = dot2(wA[16 + 4 * c + 2], hv.z, acc1);
                acc1 = dot2(wA[16 + 4 * c + 3], hv.w, acc1);
                acc2 = dot2(wA[32 + 4 * c + 0], hv.x, acc2);
                acc2 = dot2(wA[32 + 4 * c + 1], hv.y, acc2);
                acc2 = dot2(wA[32 + 4 * c + 2], hv.z, acc2);
                acc2 = dot2(wA[32 + 4 * c + 3], hv.w, acc2);
                acc3 = dot2(wA[48 + 4 * c + 0], hv.x, acc3);
                acc3 = dot2(wA[48 + 4 * c + 1], hv.y, acc3);
                acc3 = dot2(wA[48 + 4 * c + 2], hv.z, acc3);
                acc3 = dot2(wA[48 + 4 * c + 3], hv.w, acc3);
            }
        }

        // wave-wide butterfly reduce (4 rows)
        #pragma unroll
        for (int off = 32; off > 0; off >>= 1) {
            acc0 += __shfl_xor(acc0, off, 64);
            acc1 += __shfl_xor(acc1, off, 64);
            acc2 += __shfl_xor(acc2, off, 64);
            acc3 += __shfl_xor(acc3, off, 64);
        }

        if (k == 0) {
            float h0 = fast_tanh(acc0 + bh4.x + (l == 0 ? xv.x : 0.f));
            float h1 = fast_tanh(acc1 + bh4.y + (l == 0 ? xv.y : 0.f));
            float h2 = fast_tanh(acc2 + bh4.z + (l == 0 ? xv.z : 0.f));
            float h3 = fast_tanh(acc3 + bh4.w + (l == 0 ? xv.w : 0.f));
            uint64 hw = (uint64)packh2(h0, h1) | ((uint64)packh2(h2, h3) << 32);
            ST_AGENT((uint64*)&histL[(size_t)t * H2 + (r0 >> 1)], hw);
            // drain so the NEXT iteration's ready-flag store (after barrier C)
            // cannot become visible before the data.
            asm volatile("s_waitcnt vmcnt(0)" ::: "memory");
            if (t == S_LEN - 1) {
                hfin[l * HID + r0]     = h0;
                hfin[l * HID + r0 + 1] = h1;
                hfin[l * HID + r0 + 2] = h2;
                hfin[l * HID + r0 + 3] = h3;
            }
        }
        __syncthreads();                 // C: all data stores drained
    }
    // final epoch: h(S-1) visible (consumers poll prev >= t+1 = S)
    if (tid == 0) ST_AGENT(&ready[g], (uint32)S_LEN);
}

// ---------------------------------------------------------------------------
// GEMM1: xin[t][r] = sum_k x[t][k] * Wx[r][k]   (fp32 NT-GEMM, 64x64 tile)
// ---------------------------------------------------------------------------
__global__ __launch_bounds__(256) void gemm_xin(
    const float* __restrict__ A, const float* __restrict__ B,
    float* __restrict__ C, int M, int N, int K)
{
    __shared__ float As[32][65];
    __shared__ float Bs[32][65];

    const int tid = threadIdx.x;
    const int tx = tid & 15, ty = tid >> 4;
    const int i0 = blockIdx.y * 64;
    const int j0 = blockIdx.x * 64;

    float acc[4][4] = {};

    for (int k0 = 0; k0 < K; k0 += 32) {
        #pragma unroll
        for (int ld = tid; ld < 64 * 32; ld += 256) {
            const int r = ld >> 5, kk = ld & 31;
            As[kk][r] = A[(size_t)(i0 + r) * K + k0 + kk];
            Bs[kk][r] = B[(size_t)(j0 + r) * K + k0 + kk];
        }
        __syncthreads();
        #pragma unroll
        for (int kk = 0; kk < 32; ++kk) {
            float a[4], b[4];
            #pragma unroll
            for (int u = 0; u < 4; ++u) a[u] = As[kk][ty * 4 + u];
            #pragma unroll
            for (int u = 0; u < 4; ++u) b[u] = Bs[kk][tx * 4 + u];
            #pragma unroll
            for (int u = 0; u < 4; ++u)
                #pragma unroll
                for (int q = 0; q < 4; ++q)
                    acc[u][q] += a[u] * b[q];
        }
        __syncthreads();
    }
    #pragma unroll
    for (int u = 0; u < 4; ++u)
        #pragma unroll
        for (int q = 0; q < 4; ++q)
            C[(size_t)(i0 + ty * 4 + u) * N + j0 + tx * 4 + q] = acc[u][q];
}

// ---------------------------------------------------------------------------
// Output GEMM: ys[t][j] = sum_k h3[t][k] * Wy[j][k] + By[j]
// A = hist[3] packed half2 [2048][1024u], B = Wy fp32 [1024][2048].
// ---------------------------------------------------------------------------
__global__ __launch_bounds__(256) void gemm_out(
    const uint32* __restrict__ A2, const float* __restrict__ B,
    const float* __restrict__ bias, float* __restrict__ C)
{
    __shared__ float As[32][65];
    __shared__ float Bs[32][65];

    const int tid = threadIdx.x;
    const int tx = tid & 15, ty = tid >> 4;
    const int i0 = blockIdx.y * 64;   // over M = S_LEN
    const int j0 = blockIdx.x * 64;   // over N = IN_SZ

    float acc[4][4] = {};

    for (int k0 = 0; k0 < HID; k0 += 32) {
        #pragma unroll
        for (int ld = tid; ld < 1024; ld += 256) {   // A: 64 rows x 16 uints
            const int r = ld >> 4, kk2 = ld & 15;
            half2_t h = __builtin_bit_cast(half2_t,
                A2[(size_t)(i0 + r) * H2 + (k0 >> 1) + kk2]);
            As[2 * kk2][r]     = (float)h.x;
            As[2 * kk2 + 1][r] = (float)h.y;
        }
        #pragma unroll
        for (int ld = tid; ld < 2048; ld += 256) {   // B: 64 rows x 32 k
            const int rn = ld >> 5, kk = ld & 31;
            Bs[kk][rn] = B[(size_t)(j0 + rn) * HID + k0 + kk];
        }
        __syncthreads();
        #pragma unroll
        for (int kk = 0; kk < 32; ++kk) {
            float a[4], b[4];
            #pragma unroll
            for (int u = 0; u < 4; ++u) a[u] = As[kk][ty * 4 + u];
            #pragma unroll
            for (int u = 0; u < 4; ++u) b[u] = Bs[kk][tx * 4 + u];
            #pragma unroll
            for (int u = 0; u < 4; ++u)
                #pragma unroll
                for (int q = 0; q < 4; ++q)
                    acc[u][q] += a[u] * b[q];
        }
        __syncthreads();
    }
    #pragma unroll
    for (int u = 0; u < 4; ++u)
        #pragma unroll
        for (int q = 0; q < 4; ++q) {
            const int i = i0 + ty * 4 + u;
            const int j = j0 + tx * 4 + q;
            C[(size_t)i * IN_SZ + j] = acc[u][q] + bias[j];
        }
}

// ---------------------------------------------------------------------------
extern "C" void kernel_launch(void* const* d_in, const int* in_sizes, int n_in,
                              void* d_out, int out_size, void* d_ws, size_t ws_size,
                              hipStream_t stream) {
    const float* x   = (const float*)d_in[0];
    const float* Wh  = (const float*)d_in[1];
    const float* Whh = (const float*)d_in[2];
    const float* Wx  = (const float*)d_in[3];
    const float* Wy  = (const float*)d_in[4];
    const float* Bh  = (const float*)d_in[5];
    const float* By  = (const float*)d_in[6];

    float* out  = (float*)d_out;
    float* hfin = out + (size_t)S_LEN * IN_SZ;

    // ws layout: [xin S*H fp32 = 16MB][hist 4*S*H2 u32 = 32MB]  (= 48MB,
    // identical footprint to the verified rounds -- nothing past hist).
    float*  xin  = (float*)d_ws;
    uint32* hist = (uint32*)d_ws + (size_t)S_LEN * HID;

    // epoch flags live in the first 1KB of ys (d_out) -- guaranteed
    // allocated; gemm_out fully overwrites ys afterwards in stream order.
    uint32* ready = (uint32*)d_out;

    // zero the per-WG epoch flags only (no 32MB sentinel memset needed)
    hipMemsetAsync(ready, 0, NLAY * 64 * sizeof(uint32), stream);

    // xin = x @ Wx^T  (M=S, N=H, K=IN)
    gemm_xin<<<dim3(HID / 64, S_LEN / 64), 256, 0, stream>>>(
        x, Wx, xin, S_LEN, HID, IN_SZ);

    // the sequential scan (persistent, 1 WG per CU)
    rnn_scan<<<NWG, BLK, 0, stream>>>(Wh, Whh, xin, Bh, hfin, hist, ready);

    // ys = H3 @ Wy^T + By  -> d_out
    gemm_out<<<dim3(IN_SZ / 64, S_LEN / 64), 256, 0, stream>>>(
        hist + (size_t)3 * S_LEN * H2, Wy, By, out);
}

// Round 6
// 5794.495 us; speedup vs baseline: 1.7589x; 1.7589x over previous
//
#include <hip/hip_runtime.h>
#include <math.h>

// ---------------------------------------------------------------------------
// RNNv2 round 13: r11 family (data-as-signal + escalating backoff, 5272us),
// refined. r12's flag protocol REGRESSED 2x (10.1ms): its per-step serial
// L3 round-trips (vmcnt(0) ack + flag visibility + separate one-shot data
// load) cost more than its traffic savings. Data-as-signal keeps stores
// fire-and-forget and makes the poll read BE the data read.
// Changes vs r11:
//  (1) 8-byte poll units: producer's single 8B store (4 packed rows) ==
//      one consumer thread's dwordx2 poll unit. One load + one compare per
//      buffer (was 2+2), atomic arrival per unit, half the poll traffic.
//  (2) deeper backoff cap: 2 -> 8 -> 32-repeat (was cap 16). r7->r11 showed
//      deeper throttle monotonically helps (fabric congestion relief).
// Everything else byte-identical to r11.
// d_out = [ys (S*IN) | h_final (L*H)]
// ---------------------------------------------------------------------------

typedef unsigned int uint32;
typedef unsigned long long uint64;
typedef _Float16 half2_t __attribute__((ext_vector_type(2)));

#define S_LEN 2048
#define IN_SZ 1024
#define HID   2048
#define NLAY  4
#define NWG   256
#define BLK   512
#define H2    1024   // uints per packed h vector (HID/2)
#define SENT  0x7F7F7F7Fu
#define SENT64 0x7F7F7F7F7F7F7F7FULL

#define LD_AGENT64(p) __hip_atomic_load((p), __ATOMIC_RELAXED, __HIP_MEMORY_SCOPE_AGENT)
#define ST_AGENT(p,v) __hip_atomic_store((p), (v), __ATOMIC_RELAXED, __HIP_MEMORY_SCOPE_AGENT)

__device__ __forceinline__ float dot2(uint32 a, uint32 b, float c) {
    return __builtin_amdgcn_fdot2(__builtin_bit_cast(half2_t, a),
                                  __builtin_bit_cast(half2_t, b), c, false);
}
__device__ __forceinline__ uint32 packh2(float x, float y) {
    half2_t h; h.x = (_Float16)x; h.y = (_Float16)y;   // RNE converts
    return __builtin_bit_cast(uint32, h);
}
__device__ __forceinline__ float fast_tanh(float x) {
#if __has_builtin(__builtin_amdgcn_exp2f) && __has_builtin(__builtin_amdgcn_rcpf)
    // tanh(x) = sign(x) * (1 - 2/(exp2(2*log2e*|x|) + 1)); abs err ~1e-6
    float a = fabsf(x);
    float e = __builtin_amdgcn_exp2f(a * 2.885390081777927f);
    float r = 1.f - 2.f * __builtin_amdgcn_rcpf(e + 1.f);
    return copysignf(r, x);
#else
    return tanhf(x);
#endif
}

__global__ __launch_bounds__(BLK, 2) void rnn_scan(
    const float* __restrict__ Wh,   // [4][H][H]
    const float* __restrict__ Whh,  // [3][H][H]
    const float* __restrict__ xin,  // [S][H]  (x @ Wx^T, fp32)
    const float* __restrict__ Bh,   // [4][H]
    float* __restrict__ hfin,       // [4][H] (tail of d_out)
    uint32* hist)                   // [4][S][H2] packed half2, sentinel-filled
{
    __shared__ __align__(16) uint32 sh_own[2][H2];
    __shared__ __align__(16) uint32 sh_prev[2][H2];

    const int g   = blockIdx.x;
    const int l   = g >> 6;          // layer 0..3 (wave-uniform)
    const int w   = g & 63;          // wg within layer
    const int tid = threadIdx.x;
    const int v   = tid >> 6;        // wave 0..7
    const int k   = tid & 63;        // lane
    const int r0  = w * 32 + v * 4;  // first of this wave's 4 rows

    // ---- one-time: load + pack weights into registers --------------------
    // Chunk c (0..3): lane k covers cols 8k+512c..+7 = uint4 index k+64c of
    // the packed h row. wA[16*rr + 4c + q] = Wh row rr; wB likewise for Whh.
    uint32 wA[64], wB[64];
    const float4 bh4 = *(const float4*)(Bh + l * HID + r0);

    #pragma unroll
    for (int rr = 0; rr < 4; ++rr) {
        const float* wr = Wh + ((size_t)l * HID + r0 + rr) * HID;
        #pragma unroll
        for (int j = 0; j < 4; ++j) {
            const float* p = wr + 8 * k + 512 * j;
            float4 f0 = *(const float4*)p;
            float4 f1 = *(const float4*)(p + 4);
            wA[16 * rr + 4 * j + 0] = packh2(f0.x, f0.y);
            wA[16 * rr + 4 * j + 1] = packh2(f0.z, f0.w);
            wA[16 * rr + 4 * j + 2] = packh2(f1.x, f1.y);
            wA[16 * rr + 4 * j + 3] = packh2(f1.z, f1.w);
        }
    }
    if (l > 0) {
        #pragma unroll
        for (int rr = 0; rr < 4; ++rr) {
            const float* wr2 = Whh + ((size_t)(l - 1) * HID + r0 + rr) * HID;
            #pragma unroll
            for (int j = 0; j < 4; ++j) {
                const float* p = wr2 + 8 * k + 512 * j;
                float4 f0 = *(const float4*)p;
                float4 f1 = *(const float4*)(p + 4);
                wB[16 * rr + 4 * j + 0] = packh2(f0.x, f0.y);
                wB[16 * rr + 4 * j + 1] = packh2(f0.z, f0.w);
                wB[16 * rr + 4 * j + 2] = packh2(f1.x, f1.y);
                wB[16 * rr + 4 * j + 3] = packh2(f1.z, f1.w);
            }
        }
    }

    uint32* histL = hist + (size_t)l * S_LEN * H2;
    uint32* histP = hist + (size_t)(l - 1) * S_LEN * H2;  // only if l>0
    const bool needPrev = (l > 0);

    // ---- timestep loop ----------------------------------------------------
    // Thread tid polls/stages the 8B unit covering words {2tid, 2tid+1} of
    // each needed h vector. Producer wave (w,v)'s single 8B store == unit
    // w*8+v: arrival is atomic per unit.
    for (int t = 0; t < S_LEN; ++t) {
        const int  p       = t & 1;
        const bool needOwn = (t > 0);

        // layer 0: prefetch xin quad early (static data, rides across barrier)
        float4 xv = make_float4(0.f, 0.f, 0.f, 0.f);
        if (l == 0 && k == 0) xv = *(const float4*)(xin + (size_t)t * HID + r0);

        // clear this thread's 8B units of parity buffer p (data-as-signal).
        // Safe: barrier at step t-1 ordered all waves' compute(t-2) reads of
        // buffer p before this write.
        ((uint64*)sh_own [p])[tid] = SENT64;
        ((uint64*)sh_prev[p])[tid] = SENT64;

        // lgkmcnt-only barrier: clears visible WG-wide, but the producer's
        // agent h-store (vmcnt) is NOT drained -> stays fire-and-forget.
        asm volatile("s_waitcnt lgkmcnt(0)" ::: "memory");
        __builtin_amdgcn_s_barrier();

        // ---- stage: spin on this thread's own+prev 8B units --------------
        // Escalating backoff (congestion relief, confirmed r7->r11):
        // miss 1 -> sleep(2), miss 2 -> sleep(8), then sleep(32) (~2048cy).
        __builtin_amdgcn_s_setprio(0);
        {
            bool dO = !needOwn, dP = !needPrev;
            const size_t tOwn = (size_t)(needOwn ? t - 1 : 0) * H2;
            const uint64* pO = (const uint64*)(histL + tOwn) + tid;
            const uint64* pP = (const uint64*)(histP + (size_t)t * H2) + tid;
            int it = 0;
            while (!(dO & dP)) {
                if (!dP) { uint64 b = LD_AGENT64(pP);
                    if (b != SENT64) { ((uint64*)sh_prev[p])[tid] = b; dP = true; } }
                if (!dO) { uint64 a = LD_AGENT64(pO);
                    if (a != SENT64) { ((uint64*)sh_own[p])[tid] = a; dO = true; } }
                if (dO & dP) break;
                if (it == 0)      __builtin_amdgcn_s_sleep(2);
                else if (it == 1) __builtin_amdgcn_s_sleep(8);
                else              __builtin_amdgcn_s_sleep(32);
                ++it;
            }
        }
        __builtin_amdgcn_s_setprio(1);

        // ---- compute: bulk vector re-read until sentinel-free, then dot --
        float acc0 = 0.f, acc1 = 0.f, acc2 = 0.f, acc3 = 0.f;

        if (needPrev) {
            uint4 gv[4];
            for (;;) {
                bool bad = false;
                #pragma unroll
                for (int c = 0; c < 4; ++c) {
                    gv[c] = ((const uint4*)sh_prev[p])[k + 64 * c];
                    bad |= (gv[c].x == SENT) | (gv[c].y == SENT) |
                           (gv[c].z == SENT) | (gv[c].w == SENT);
                }
                if (!bad) break;
                __builtin_amdgcn_s_sleep(1);
                asm volatile("" ::: "memory");   // force LDS re-read
            }
            #pragma unroll
            for (int c = 0; c < 4; ++c) {
                acc0 = dot2(wB[4 * c + 0], gv[c].x, acc0);
                acc0 = dot2(wB[4 * c + 1], gv[c].y, acc0);
                acc0 = dot2(wB[4 * c + 2], gv[c].z, acc0);
                acc0 = dot2(wB[4 * c + 3], gv[c].w, acc0);
                acc1 = dot2(wB[16 + 4 * c + 0], gv[c].x, acc1);
                acc1 = dot2(wB[16 + 4 * c + 1], gv[c].y, acc1);
                acc1 = dot2(wB[16 + 4 * c + 2], gv[c].z, acc1);
                acc1 = dot2(wB[16 + 4 * c + 3], gv[c].w, acc1);
                acc2 = dot2(wB[32 + 4 * c + 0], gv[c].x, acc2);
                acc2 = dot2(wB[32 + 4 * c + 1], gv[c].y, acc2);
                acc2 = dot2(wB[32 + 4 * c + 2], gv[c].z, acc2);
                acc2 = dot2(wB[32 + 4 * c + 3], gv[c].w, acc2);
                acc3 = dot2(wB[48 + 4 * c + 0], gv[c].x, acc3);
                acc3 = dot2(wB[48 + 4 * c + 1], gv[c].y, acc3);
                acc3 = dot2(wB[48 + 4 * c + 2], gv[c].z, acc3);
                acc3 = dot2(wB[48 + 4 * c + 3], gv[c].w, acc3);
            }
        }

        if (needOwn) {
            uint4 hv[4];
            for (;;) {
                bool bad = false;
                #pragma unroll
                for (int c = 0; c < 4; ++c) {
                    hv[c] = ((const uint4*)sh_own[p])[k + 64 * c];
                    bad |= (hv[c].x == SENT) | (hv[c].y == SENT) |
                           (hv[c].z == SENT) | (hv[c].w == SENT);
                }
                if (!bad) break;
                __builtin_amdgcn_s_sleep(1);
                asm volatile("" ::: "memory");   // force LDS re-read
            }
            #pragma unroll
            for (int c = 0; c < 4; ++c) {
                acc0 = dot2(wA[4 * c + 0], hv[c].x, acc0);
                acc0 = dot2(wA[4 * c + 1], hv[c].y, acc0);
                acc0 = dot2(wA[4 * c + 2], hv[c].z, acc0);
                acc0 = dot2(wA[4 * c + 3], hv[c].w, acc0);
                acc1 = dot2(wA[16 + 4 * c + 0], hv[c].x, acc1);
                acc1 = dot2(wA[16 + 4 * c + 1], hv[c].y, acc1);
                acc1 = dot2(wA[16 + 4 * c + 2], hv[c].z, acc1);
                acc1 = dot2(wA[16 + 4 * c + 3], hv[c].w, acc1);
                acc2 = dot2(wA[32 + 4 * c + 0], hv[c].x, acc2);
                acc2 = dot2(wA[32 + 4 * c + 1], hv[c].y, acc2);
                acc2 = dot2(wA[32 + 4 * c + 2], hv[c].z, acc2);
                acc2 = dot2(wA[32 + 4 * c + 3], hv[c].w, acc2);
                acc3 = dot2(wA[48 + 4 * c + 0], hv[c].x, acc3);
                acc3 = dot2(wA[48 + 4 * c + 1], hv[c].y, acc3);
                acc3 = dot2(wA[48 + 4 * c + 2], hv[c].z, acc3);
                acc3 = dot2(wA[48 + 4 * c + 3], hv[c].w, acc3);
            }
        }

        // wave-wide butterfly reduce (4 rows)
        #pragma unroll
        for (int off = 32; off > 0; off >>= 1) {
            acc0 += __shfl_xor(acc0, off, 64);
            acc1 += __shfl_xor(acc1, off, 64);
            acc2 += __shfl_xor(acc2, off, 64);
            acc3 += __shfl_xor(acc3, off, 64);
        }

        if (k == 0) {
            float h0 = fast_tanh(acc0 + bh4.x + (l == 0 ? xv.x : 0.f));
            float h1 = fast_tanh(acc1 + bh4.y + (l == 0 ? xv.y : 0.f));
            float h2 = fast_tanh(acc2 + bh4.z + (l == 0 ? xv.z : 0.f));
            float h3 = fast_tanh(acc3 + bh4.w + (l == 0 ? xv.w : 0.f));
            // single 8B store IS the release signal (words become non-NaN)
            uint64 hw = (uint64)packh2(h0, h1) | ((uint64)packh2(h2, h3) << 32);
            ST_AGENT((uint64*)&histL[(size_t)t * H2 + (r0 >> 1)], hw);
            if (t == S_LEN - 1) {
                hfin[l * HID + r0]     = h0;
                hfin[l * HID + r0 + 1] = h1;
                hfin[l * HID + r0 + 2] = h2;
                hfin[l * HID + r0 + 3] = h3;
            }
        }
    }
}

// ---------------------------------------------------------------------------
// GEMM1: xin[t][r] = sum_k x[t][k] * Wx[r][k]   (fp32 NT-GEMM, 64x64 tile)
// ---------------------------------------------------------------------------
__global__ __launch_bounds__(256) void gemm_xin(
    const float* __restrict__ A, const float* __restrict__ B,
    float* __restrict__ C, int M, int N, int K)
{
    __shared__ float As[32][65];
    __shared__ float Bs[32][65];

    const int tid = threadIdx.x;
    const int tx = tid & 15, ty = tid >> 4;
    const int i0 = blockIdx.y * 64;
    const int j0 = blockIdx.x * 64;

    float acc[4][4] = {};

    for (int k0 = 0; k0 < K; k0 += 32) {
        #pragma unroll
        for (int ld = tid; ld < 64 * 32; ld += 256) {
            const int r = ld >> 5, kk = ld & 31;
            As[kk][r] = A[(size_t)(i0 + r) * K + k0 + kk];
            Bs[kk][r] = B[(size_t)(j0 + r) * K + k0 + kk];
        }
        __syncthreads();
        #pragma unroll
        for (int kk = 0; kk < 32; ++kk) {
            float a[4], b[4];
            #pragma unroll
            for (int u = 0; u < 4; ++u) a[u] = As[kk][ty * 4 + u];
            #pragma unroll
            for (int u = 0; u < 4; ++u) b[u] = Bs[kk][tx * 4 + u];
            #pragma unroll
            for (int u = 0; u < 4; ++u)
                #pragma unroll
                for (int q = 0; q < 4; ++q)
                    acc[u][q] += a[u] * b[q];
        }
        __syncthreads();
    }
    #pragma unroll
    for (int u = 0; u < 4; ++u)
        #pragma unroll
        for (int q = 0; q < 4; ++q)
            C[(size_t)(i0 + ty * 4 + u) * N + j0 + tx * 4 + q] = acc[u][q];
}

// ---------------------------------------------------------------------------
// Output GEMM: ys[t][j] = sum_k h3[t][k] * Wy[j][k] + By[j]
// A = hist[3] packed half2 [2048][1024u], B = Wy fp32 [1024][2048].
// ---------------------------------------------------------------------------
__global__ __launch_bounds__(256) void gemm_out(
    const uint32* __restrict__ A2, const float* __restrict__ B,
    const float* __restrict__ bias, float* __restrict__ C)
{
    __shared__ float As[32][65];
    __shared__ float Bs[32][65];

    const int tid = threadIdx.x;
    const int tx = tid & 15, ty = tid >> 4;
    const int i0 = blockIdx.y * 64;   // over M = S_LEN
    const int j0 = blockIdx.x * 64;   // over N = IN_SZ

    float acc[4][4] = {};

    for (int k0 = 0; k0 < HID; k0 += 32) {
        #pragma unroll
        for (int ld = tid; ld < 1024; ld += 256) {   // A: 64 rows x 16 uints
            const int r = ld >> 4, kk2 = ld & 15;
            half2_t h = __builtin_bit_cast(half2_t,
                A2[(size_t)(i0 + r) * H2 + (k0 >> 1) + kk2]);
            As[2 * kk2][r]     = (float)h.x;
            As[2 * kk2 + 1][r] = (float)h.y;
        }
        #pragma unroll
        for (int ld = tid; ld < 2048; ld += 256) {   // B: 64 rows x 32 k
            const int rn = ld >> 5, kk = ld & 31;
            Bs[kk][rn] = B[(size_t)(j0 + rn) * HID + k0 + kk];
        }
        __syncthreads();
        #pragma unroll
        for (int kk = 0; kk < 32; ++kk) {
            float a[4], b[4];
            #pragma unroll
            for (int u = 0; u < 4; ++u) a[u] = As[kk][ty * 4 + u];
            #pragma unroll
            for (int u = 0; u < 4; ++u) b[u] = Bs[kk][tx * 4 + u];
            #pragma unroll
            for (int u = 0; u < 4; ++u)
                #pragma unroll
                for (int q = 0; q < 4; ++q)
                    acc[u][q] += a[u] * b[q];
        }
        __syncthreads();
    }
    #pragma unroll
    for (int u = 0; u < 4; ++u)
        #pragma unroll
        for (int q = 0; q < 4; ++q) {
            const int i = i0 + ty * 4 + u;
            const int j = j0 + tx * 4 + q;
            C[(size_t)i * IN_SZ + j] = acc[u][q] + bias[j];
        }
}

// ---------------------------------------------------------------------------
extern "C" void kernel_launch(void* const* d_in, const int* in_sizes, int n_in,
                              void* d_out, int out_size, void* d_ws, size_t ws_size,
                              hipStream_t stream) {
    const float* x   = (const float*)d_in[0];
    const float* Wh  = (const float*)d_in[1];
    const float* Whh = (const float*)d_in[2];
    const float* Wx  = (const float*)d_in[3];
    const float* Wy  = (const float*)d_in[4];
    const float* Bh  = (const float*)d_in[5];
    const float* By  = (const float*)d_in[6];

    float* out  = (float*)d_out;
    float* hfin = out + (size_t)S_LEN * IN_SZ;

    // ws layout: [xin S*H fp32 = 16 MB][hist 4*S*H2 u32 = 32 MB]
    float*  xin  = (float*)d_ws;
    uint32* hist = (uint32*)d_ws + (size_t)S_LEN * HID;

    // sentinel-fill hist: 0x7F byte -> each fp16 half = NaN (never produced)
    hipMemsetAsync(hist, 0x7F, (size_t)NLAY * S_LEN * H2 * sizeof(uint32), stream);

    // xin = x @ Wx^T  (M=S, N=H, K=IN)
    gemm_xin<<<dim3(HID / 64, S_LEN / 64), 256, 0, stream>>>(
        x, Wx, xin, S_LEN, HID, IN_SZ);

    // the sequential scan (persistent, 1 WG per CU)
    rnn_scan<<<NWG, BLK, 0, stream>>>(Wh, Whh, xin, Bh, hfin, hist);

    // ys = H3 @ Wy^T + By  -> d_out
    gemm_out<<<dim3(IN_SZ / 64, S_LEN / 64), 256, 0, stream>>>(
        hist + (size_t)3 * S_LEN * H2, Wy, By, out);
}